// Round 11
// baseline (105.846 us; speedup 1.0000x reference)
//
#include <hip/hip_runtime.h>
#include <hip/hip_bf16.h>

#define N 8192
#define D 128
#define JC 32                // j-chunks
#define CHUNK (N / JC)       // 256 cols per chunk
#define BJ 64                // cols per LDS tile
#define NT (CHUNK / BJ)      // 4 tiles per chunk
#define RBLK 512             // rows per block (4 waves x 128)
#define NRB (N / RBLK)       // 16 row-blocks
#define NLBL 100             // labels in [0,100)
#define LCH 128              // labelsum blocks
#define LR 64                // rows per labelsum block

#define K1F 14.426950408889634f    // 10 * log2(e)
#define K0F (-14.426950408889634f)

#if __has_builtin(__builtin_amdgcn_exp2f)
#define EXP2(x) __builtin_amdgcn_exp2f(x)
#else
#define EXP2(x) exp2f(x)
#endif

typedef __attribute__((ext_vector_type(8))) short bf16x8;
typedef __attribute__((ext_vector_type(4))) float f32x4;

// ---------------- Stage 0: row-normalize z -> bf16 zn, plus self-dot d_ii ----
__global__ __launch_bounds__(256) void znorm_kernel(const float* __restrict__ z,
                                                    ushort* __restrict__ zn,
                                                    float* __restrict__ dii) {
    const int wid  = threadIdx.x >> 6;
    const int lane = threadIdx.x & 63;
    const int row  = blockIdx.x * 4 + wid;       // grid = N/4 blocks
    const float2 v = reinterpret_cast<const float2*>(z + (size_t)row * D)[lane];
    float ss = v.x * v.x + v.y * v.y;
    #pragma unroll
    for (int m = 1; m < 64; m <<= 1) ss += __shfl_xor(ss, m);
    const float inv = 1.0f / fmaxf(sqrtf(ss), 1e-8f);
    __hip_bfloat16 b0 = __float2bfloat16(v.x * inv);
    __hip_bfloat16 b1 = __float2bfloat16(v.y * inv);
    ushort2 o;
    o.x = *reinterpret_cast<ushort*>(&b0);
    o.y = *reinterpret_cast<ushort*>(&b1);
    reinterpret_cast<ushort2*>(zn + (size_t)row * D)[lane] = o;
    const float f0 = __bfloat162float(b0), f1 = __bfloat162float(b1);
    float s2 = f0 * f0 + f1 * f1;
    #pragma unroll
    for (int m = 1; m < 64; m <<= 1) s2 += __shfl_xor(s2, m);
    if (lane == 0) dii[row] = s2;
}

// ---------------- Stage 0b: per-label sums + histogram (deterministic) ------
__global__ __launch_bounds__(256) void labelsum_kernel(const ushort* __restrict__ zn,
                                                       const int* __restrict__ y,
                                                       float* __restrict__ tpart,
                                                       float* __restrict__ cpart) {
    __shared__ float tl[2][NLBL][D];   // 102.4 KB
    __shared__ float ch[2][128];
    __shared__ int   ly[LR];
    const int h = threadIdx.x >> 7;
    const int d = threadIdx.x & 127;
    for (int c = 0; c < NLBL; ++c) tl[h][c][d] = 0.0f;
    if (threadIdx.x < LR) ly[threadIdx.x] = y[blockIdx.x * LR + threadIdx.x];
    __syncthreads();
    const int j0 = blockIdx.x * LR + h * 32;
    float cl = 0.0f;
    for (int j = 0; j < 32; ++j) {
        const int c = ly[h * 32 + j];
        __hip_bfloat16 hb;
        *reinterpret_cast<ushort*>(&hb) = zn[(size_t)(j0 + j) * D + d];
        tl[h][c][d] += __bfloat162float(hb);      // exclusive column: no race
        cl += (c == d) ? 1.0f : 0.0f;
    }
    ch[h][d] = cl;
    __syncthreads();
    const float* t0 = &tl[0][0][0];
    for (int idx = threadIdx.x; idx < NLBL * D; idx += 256)
        tpart[(size_t)blockIdx.x * NLBL * D + idx] = t0[idx] + t0[NLBL * D + idx];
    if (threadIdx.x < NLBL)
        cpart[blockIdx.x * NLBL + threadIdx.x] = ch[0][threadIdx.x] + ch[1][threadIdx.x];
}

// ---------------- Stage 0c: reduce partials (parallel over outputs) ---------
__global__ __launch_bounds__(256) void reduce_t_kernel(const float* __restrict__ tpart,
                                                       const float* __restrict__ cpart,
                                                       float* __restrict__ t,
                                                       float* __restrict__ cnt) {
    if (blockIdx.x < NLBL * D / 64) {
        __shared__ float s4[4][64];
        const int o  = blockIdx.x * 64 + (threadIdx.x & 63);
        const int sl = threadIdx.x >> 6;           // 4 slices x 32 chunks
        float s = 0.0f;
        #pragma unroll 8
        for (int b = sl * (LCH / 4); b < (sl + 1) * (LCH / 4); ++b)
            s += tpart[(size_t)b * NLBL * D + o];
        s4[sl][threadIdx.x & 63] = s;
        __syncthreads();
        if (threadIdx.x < 64)
            t[blockIdx.x * 64 + threadIdx.x] = s4[0][threadIdx.x] + s4[1][threadIdx.x] +
                                               s4[2][threadIdx.x] + s4[3][threadIdx.x];
    } else {
        const int c = threadIdx.x;
        if (c < NLBL) {
            float s = 0.0f;
            for (int b = 0; b < LCH; ++b) s += cpart[b * NLBL + c];
            cnt[c] = s;
        }
    }
}

// ---------------- Stage 1: LDS-shared B, double-buffered, 1 barrier/tile ----
// 4 waves/block, 128 rows/wave (a[8][4] -> AGPR file), BJ=64-col B tile in
// LDS shared by all 4 waves (4x less L1/L2 traffic than per-wave streams).
// XOR swizzle slot^=(row&7) on staging-source and ds_read (G4/T2): wave
// reads 16 rows at same col-range -> linear layout would be a 16-way bank
// conflict; swizzled read is uniform 8 accesses/bank (optimal for b128).
// Stage loads issue a full compute-phase (~4966 cyc) early (T14): vmcnt
// drain at ds_write is near-zero. One __syncthreads per tile.
__global__ __launch_bounds__(256, 2) void supcon_main(const ushort* __restrict__ zn,
                                                      float* __restrict__ pZ) {
    __shared__ ushort Bsm[2][BJ * D];   // 2 x 16 KB
    const int wid  = threadIdx.x >> 6;
    const int lane = threadIdx.x & 63;
    const int g    = lane >> 4;      // 0..3
    const int lj   = lane & 15;
    const int rowBlk = blockIdx.x & (NRB - 1);   // 16 row-blocks
    const int chunk  = blockIdx.x >> 4;          // 32 chunks
    const int rowBase = rowBlk * RBLK + wid * 128;
    const int j0 = chunk * CHUNK;

    // staging geometry: thread covers 4 chunks; chunk c -> row c*16+(tid>>4),
    // LDS slot tid&15 (linear: lane byte addr = 16*tid -> conflict-free write)
    const int srow  = threadIdx.x >> 4;          // 0..15
    const int sslot = threadIdx.x & 15;

    // A fragments: 8 M-tiles x 4 K-steps (128 regs -> AGPR file)
    bf16x8 a[8][4];
    #pragma unroll
    for (int m = 0; m < 8; ++m) {
        const ushort* rp = zn + (size_t)(rowBase + m * 16 + lj) * D;
        #pragma unroll
        for (int s = 0; s < 4; ++s)
            a[m][s] = *reinterpret_cast<const bf16x8*>(rp + s * 32 + g * 8);
    }

    float Z[8][4];
    #pragma unroll
    for (int m = 0; m < 8; ++m)
        #pragma unroll
        for (int r = 0; r < 4; ++r) Z[m][r] = 0.0f;

    // prologue: stage tile 0 (source pre-swizzled so LDS[r][slot] holds
    // global[r][slot^(r&7)]; reader applies the same XOR -> identity)
    bf16x8 st[4];
    #pragma unroll
    for (int c = 0; c < 4; ++c) {
        const int r = c * 16 + srow;
        st[c] = *reinterpret_cast<const bf16x8*>(
            zn + (size_t)(j0 + r) * D + ((sslot ^ (r & 7)) * 8));
    }
    #pragma unroll
    for (int c = 0; c < 4; ++c) {
        const int r = c * 16 + srow;
        *reinterpret_cast<bf16x8*>(&Bsm[0][r * D + sslot * 8]) = st[c];
    }
    __syncthreads();

    const f32x4 zero4 = {0.f, 0.f, 0.f, 0.f};
    #pragma unroll 1
    for (int t = 0; t < NT; ++t) {
        const int cur = t & 1;
        // issue next tile's loads NOW; they land under this tile's compute
        if (t + 1 < NT) {
            #pragma unroll
            for (int c = 0; c < 4; ++c) {
                const int r = c * 16 + srow;
                st[c] = *reinterpret_cast<const bf16x8*>(
                    zn + (size_t)(j0 + (t + 1) * BJ + r) * D + ((sslot ^ (r & 7)) * 8));
            }
            asm volatile("" ::: "memory");       // pin issue point above compute
        }
        // compute tile t from Bsm[cur]
        #pragma unroll
        for (int jt = 0; jt < 4; ++jt) {
            const int r  = jt * 16 + lj;
            const int rx = r & 7;
            bf16x8 b[4];
            #pragma unroll
            for (int s = 0; s < 4; ++s)
                b[s] = *reinterpret_cast<const bf16x8*>(
                    &Bsm[cur][r * D + (((s * 4 + g) ^ rx) * 8)]);
            f32x4 acc[8];
            #pragma unroll
            for (int m = 0; m < 8; ++m) acc[m] = zero4;
            #pragma unroll
            for (int s = 0; s < 4; ++s)
                #pragma unroll
                for (int m = 0; m < 8; ++m)
                    acc[m] = __builtin_amdgcn_mfma_f32_16x16x32_bf16(a[m][s], b[s], acc[m], 0, 0, 0);
            #pragma unroll
            for (int m = 0; m < 8; ++m)
                #pragma unroll
                for (int r2 = 0; r2 < 4; ++r2)
                    Z[m][r2] += EXP2(fmaf(acc[m][r2], K1F, K0F));   // exp(10*dot-10)
        }
        // write staged regs into the other buffer; its last readers finished
        // before the barrier at the end of the previous iteration
        if (t + 1 < NT) {
            #pragma unroll
            for (int c = 0; c < 4; ++c) {
                const int r = c * 16 + srow;
                *reinterpret_cast<bf16x8*>(&Bsm[cur ^ 1][r * D + sslot * 8]) = st[c];
            }
        }
        __syncthreads();
    }

    // sum the 16 cols within each lane group
    #pragma unroll
    for (int m = 0; m < 8; ++m)
        #pragma unroll
        for (int r = 0; r < 4; ++r)
            #pragma unroll
            for (int mk = 1; mk < 16; mk <<= 1)
                Z[m][r] += __shfl_xor(Z[m][r], mk);

    if (lj == 0) {
        #pragma unroll
        for (int m = 0; m < 8; ++m)
            #pragma unroll
            for (int r = 0; r < 4; ++r)
                pZ[chunk * N + rowBase + m * 16 + g * 4 + r] = Z[m][r];
    }
}

// ---------------- Stage 2: finalize loss ----------------
__global__ __launch_bounds__(256) void supcon_finalize(const ushort* __restrict__ zn,
                                                       const int* __restrict__ y,
                                                       const float* __restrict__ pZ,
                                                       const float* __restrict__ dii,
                                                       const float* __restrict__ t,
                                                       const float* __restrict__ cnt,
                                                       float* __restrict__ out) {
    const int wid  = threadIdx.x >> 6;
    const int lane = threadIdx.x & 63;
    const int row  = blockIdx.x * 4 + wid;
    const int c    = y[row];
    const ushort2 u = reinterpret_cast<const ushort2*>(zn + (size_t)row * D)[lane];
    const float2 tv = reinterpret_cast<const float2*>(t + (size_t)c * D)[lane];
    __hip_bfloat16 h0, h1;
    *reinterpret_cast<ushort*>(&h0) = u.x;
    *reinterpret_cast<ushort*>(&h1) = u.y;
    float dot = __bfloat162float(h0) * tv.x + __bfloat162float(h1) * tv.y;
    #pragma unroll
    for (int m = 1; m < 64; m <<= 1) dot += __shfl_xor(dot, m);
    float zs = (lane < JC) ? pZ[lane * N + row] : 0.0f;
    #pragma unroll
    for (int m = 1; m < JC; m <<= 1) zs += __shfl_xor(zs, m);
    if (lane == 0) {
        const float di = dii[row];
        const float zc = zs - EXP2(fmaf(di, K1F, K0F));   // remove self term
        const float cn = cnt[c] - 1.0f;                   // exclude self
        const float S  = dot - di;                        // exclude self
        const float denom = fmaxf(cn, 1.0f);
        const float lse   = 10.0f + logf(zc);
        out[row] = -(10.0f * S) / denom + (cn > 0.5f ? lse : 0.0f);
    }
}

extern "C" void kernel_launch(void* const* d_in, const int* in_sizes, int n_in,
                              void* d_out, int out_size, void* d_ws, size_t ws_size,
                              hipStream_t stream) {
    const float* z = (const float*)d_in[0];
    const int*   y = (const int*)d_in[1];
    float* out = (float*)d_out;

    // ws layout (~9.7 MB)
    ushort* zn    = (ushort*)d_ws;                                  // 2 MB
    float*  dii   = (float*)((char*)d_ws + (size_t)N * D * 2);      // 32 KB
    float*  tpart = dii + N;                                        // 6.55 MB
    float*  cpart = tpart + (size_t)LCH * NLBL * D;                 // 51.2 KB
    float*  t     = cpart + (size_t)LCH * NLBL;                     // 51.2 KB
    float*  cnt   = t + (size_t)NLBL * D;                           // 400 B
    float*  pZ    = cnt + NLBL;                                     // 1 MB

    znorm_kernel<<<N / 4, 256, 0, stream>>>(z, zn, dii);
    labelsum_kernel<<<LCH, 256, 0, stream>>>(zn, y, tpart, cpart);
    reduce_t_kernel<<<NLBL * D / 64 + 1, 256, 0, stream>>>(tpart, cpart, t, cnt);
    supcon_main<<<NRB * JC, 256, 0, stream>>>(zn, pZ);
    supcon_finalize<<<N / 4, 256, 0, stream>>>(zn, y, pZ, dii, t, cnt, out);
}

// Round 12
// 51.884 us; speedup vs baseline: 2.0400x; 2.0400x over previous
//
#include <hip/hip_runtime.h>
#include <hip/hip_bf16.h>

#define N 8192
#define D 128
#define JC 32                // j-chunks
#define JCH (N / JC)         // 256 cols per chunk
#define WROWS 128            // rows per wave (8 M-tiles, a[8][4] -> AGPRs)
#define NRG (N / WROWS)      // 64 row-groups
#define NLBL 100             // labels in [0,100)
#define LCH 128              // labelsum blocks
#define LR 64                // rows per labelsum block

#define K1F 14.426950408889634f    // 10 * log2(e)
#define K0F (-14.426950408889634f)

#if __has_builtin(__builtin_amdgcn_exp2f)
#define EXP2(x) __builtin_amdgcn_exp2f(x)
#else
#define EXP2(x) exp2f(x)
#endif

typedef __attribute__((ext_vector_type(8))) short bf16x8;
typedef __attribute__((ext_vector_type(4))) float f32x4;

// ---------------- Stage 0: row-normalize z -> bf16 zn, plus self-dot d_ii ----
__global__ __launch_bounds__(256) void znorm_kernel(const float* __restrict__ z,
                                                    ushort* __restrict__ zn,
                                                    float* __restrict__ dii) {
    const int wid  = threadIdx.x >> 6;
    const int lane = threadIdx.x & 63;
    const int row  = blockIdx.x * 4 + wid;       // grid = N/4 blocks
    const float2 v = reinterpret_cast<const float2*>(z + (size_t)row * D)[lane];
    float ss = v.x * v.x + v.y * v.y;
    #pragma unroll
    for (int m = 1; m < 64; m <<= 1) ss += __shfl_xor(ss, m);
    const float inv = 1.0f / fmaxf(sqrtf(ss), 1e-8f);
    __hip_bfloat16 b0 = __float2bfloat16(v.x * inv);
    __hip_bfloat16 b1 = __float2bfloat16(v.y * inv);
    ushort2 o;
    o.x = *reinterpret_cast<ushort*>(&b0);
    o.y = *reinterpret_cast<ushort*>(&b1);
    reinterpret_cast<ushort2*>(zn + (size_t)row * D)[lane] = o;
    const float f0 = __bfloat162float(b0), f1 = __bfloat162float(b1);
    float s2 = f0 * f0 + f1 * f1;
    #pragma unroll
    for (int m = 1; m < 64; m <<= 1) s2 += __shfl_xor(s2, m);
    if (lane == 0) dii[row] = s2;
}

// ---------------- Stage 0b: per-label sums + histogram (deterministic) ------
__global__ __launch_bounds__(256) void labelsum_kernel(const ushort* __restrict__ zn,
                                                       const int* __restrict__ y,
                                                       float* __restrict__ tpart,
                                                       float* __restrict__ cpart) {
    __shared__ float tl[2][NLBL][D];   // 102.4 KB
    __shared__ float ch[2][128];
    __shared__ int   ly[LR];
    const int h = threadIdx.x >> 7;
    const int d = threadIdx.x & 127;
    for (int c = 0; c < NLBL; ++c) tl[h][c][d] = 0.0f;
    if (threadIdx.x < LR) ly[threadIdx.x] = y[blockIdx.x * LR + threadIdx.x];
    __syncthreads();
    const int j0 = blockIdx.x * LR + h * 32;
    float cl = 0.0f;
    for (int j = 0; j < 32; ++j) {
        const int c = ly[h * 32 + j];
        __hip_bfloat16 hb;
        *reinterpret_cast<ushort*>(&hb) = zn[(size_t)(j0 + j) * D + d];
        tl[h][c][d] += __bfloat162float(hb);      // exclusive column: no race
        cl += (c == d) ? 1.0f : 0.0f;
    }
    ch[h][d] = cl;
    __syncthreads();
    const float* t0 = &tl[0][0][0];
    for (int idx = threadIdx.x; idx < NLBL * D; idx += 256)
        tpart[(size_t)blockIdx.x * NLBL * D + idx] = t0[idx] + t0[NLBL * D + idx];
    if (threadIdx.x < NLBL)
        cpart[blockIdx.x * NLBL + threadIdx.x] = ch[0][threadIdx.x] + ch[1][threadIdx.x];
}

// ---------------- Stage 0c: reduce partials (parallel over outputs) ---------
__global__ __launch_bounds__(256) void reduce_t_kernel(const float* __restrict__ tpart,
                                                       const float* __restrict__ cpart,
                                                       float* __restrict__ t,
                                                       float* __restrict__ cnt) {
    if (blockIdx.x < NLBL * D / 64) {
        __shared__ float s4[4][64];
        const int o  = blockIdx.x * 64 + (threadIdx.x & 63);
        const int sl = threadIdx.x >> 6;           // 4 slices x 32 chunks
        float s = 0.0f;
        #pragma unroll 8
        for (int b = sl * (LCH / 4); b < (sl + 1) * (LCH / 4); ++b)
            s += tpart[(size_t)b * NLBL * D + o];
        s4[sl][threadIdx.x & 63] = s;
        __syncthreads();
        if (threadIdx.x < 64)
            t[blockIdx.x * 64 + threadIdx.x] = s4[0][threadIdx.x] + s4[1][threadIdx.x] +
                                               s4[2][threadIdx.x] + s4[3][threadIdx.x];
    } else {
        const int c = threadIdx.x;
        if (c < NLBL) {
            float s = 0.0f;
            for (int b = 0; b < LCH; ++b) s += cpart[b * NLBL + c];
            cnt[c] = s;
        }
    }
}

// ---------------- Stage 1: streaming MFMA, register-clean ----------------
// R8/R10 structure (2048 independent waves, 128 rows x 256 cols per wave,
// a[8][4] in AGPRs, launch_bounds(256,2)) + ONE change: NO ping-pong -- a
// single b[4] set, serial load-then-use. Live regs ~= 128(a)+16(b)+32(Z)
// +32(acc)+~15(addr) ~= 223 <= 256: the allocator fits 2 waves/SIMD with
// ZERO spill (R8's ping-pong needed ~276 -> quiet spill was the ceiling).
// Load latency is covered by the other resident wave's ~900-cyc compute
// phase and the previous iteration's 32-exp VALU drain.
__global__ __launch_bounds__(256, 2) void supcon_main(const ushort* __restrict__ zn,
                                                      float* __restrict__ pZ) {
    const int wid  = threadIdx.x >> 6;
    const int lane = threadIdx.x & 63;
    const int g    = lane >> 4;      // 0..3
    const int lj   = lane & 15;
    const int gw   = blockIdx.x * 4 + wid;       // 0..2047
    const int rowGrp = gw >> 5;                  // 64 row-groups
    const int chunk  = gw & 31;                  // 32 col-chunks
    const int rowBase = rowGrp * WROWS;
    const int j0 = chunk * JCH;

    // A fragments: 8 M-tiles x 4 K-steps (128 regs -> AGPR file)
    bf16x8 a[8][4];
    #pragma unroll
    for (int m = 0; m < 8; ++m) {
        const ushort* rp = zn + (size_t)(rowBase + m * 16 + lj) * D;
        #pragma unroll
        for (int s = 0; s < 4; ++s)
            a[m][s] = *reinterpret_cast<const bf16x8*>(rp + s * 32 + g * 8);
    }

    float Z[8][4];
    #pragma unroll
    for (int m = 0; m < 8; ++m)
        #pragma unroll
        for (int r = 0; r < 4; ++r) Z[m][r] = 0.0f;

    const f32x4 zero4 = {0.f, 0.f, 0.f, 0.f};
    const ushort* jp = zn + (size_t)(j0 + lj) * D + g * 8;

    #pragma unroll 1
    for (int it = 0; it < JCH / 16; ++it) {      // 16 iterations, 16 cols each
        bf16x8 b[4];
        #pragma unroll
        for (int s = 0; s < 4; ++s)
            b[s] = *reinterpret_cast<const bf16x8*>(jp + s * 32);
        f32x4 acc[8];
        #pragma unroll
        for (int m = 0; m < 8; ++m) acc[m] = zero4;
        // k-outer / m-inner: adjacent MFMAs independent -> full ILP
        #pragma unroll
        for (int s = 0; s < 4; ++s)
            #pragma unroll
            for (int m = 0; m < 8; ++m)
                acc[m] = __builtin_amdgcn_mfma_f32_16x16x32_bf16(a[m][s], b[s], acc[m], 0, 0, 0);
        #pragma unroll
        for (int m = 0; m < 8; ++m)
            #pragma unroll
            for (int r = 0; r < 4; ++r)
                Z[m][r] += EXP2(fmaf(acc[m][r], K1F, K0F));   // exp(10*dot - 10)
        jp += 16 * D;
    }

    // sum the 16 cols within each lane group
    #pragma unroll
    for (int m = 0; m < 8; ++m)
        #pragma unroll
        for (int r = 0; r < 4; ++r)
            #pragma unroll
            for (int mk = 1; mk < 16; mk <<= 1)
                Z[m][r] += __shfl_xor(Z[m][r], mk);

    if (lj == 0) {
        #pragma unroll
        for (int m = 0; m < 8; ++m)
            #pragma unroll
            for (int r = 0; r < 4; ++r)
                pZ[chunk * N + rowBase + m * 16 + g * 4 + r] = Z[m][r];
    }
}

// ---------------- Stage 2: finalize loss ----------------
__global__ __launch_bounds__(256) void supcon_finalize(const ushort* __restrict__ zn,
                                                       const int* __restrict__ y,
                                                       const float* __restrict__ pZ,
                                                       const float* __restrict__ dii,
                                                       const float* __restrict__ t,
                                                       const float* __restrict__ cnt,
                                                       float* __restrict__ out) {
    const int wid  = threadIdx.x >> 6;
    const int lane = threadIdx.x & 63;
    const int row  = blockIdx.x * 4 + wid;
    const int c    = y[row];
    const ushort2 u = reinterpret_cast<const ushort2*>(zn + (size_t)row * D)[lane];
    const float2 tv = reinterpret_cast<const float2*>(t + (size_t)c * D)[lane];
    __hip_bfloat16 h0, h1;
    *reinterpret_cast<ushort*>(&h0) = u.x;
    *reinterpret_cast<ushort*>(&h1) = u.y;
    float dot = __bfloat162float(h0) * tv.x + __bfloat162float(h1) * tv.y;
    #pragma unroll
    for (int m = 1; m < 64; m <<= 1) dot += __shfl_xor(dot, m);
    float zs = (lane < JC) ? pZ[lane * N + row] : 0.0f;
    #pragma unroll
    for (int m = 1; m < JC; m <<= 1) zs += __shfl_xor(zs, m);
    if (lane == 0) {
        const float di = dii[row];
        const float zc = zs - EXP2(fmaf(di, K1F, K0F));   // remove self term
        const float cn = cnt[c] - 1.0f;                   // exclude self
        const float S  = dot - di;                        // exclude self
        const float denom = fmaxf(cn, 1.0f);
        const float lse   = 10.0f + logf(zc);
        out[row] = -(10.0f * S) / denom + (cn > 0.5f ? lse : 0.0f);
    }
}

extern "C" void kernel_launch(void* const* d_in, const int* in_sizes, int n_in,
                              void* d_out, int out_size, void* d_ws, size_t ws_size,
                              hipStream_t stream) {
    const float* z = (const float*)d_in[0];
    const int*   y = (const int*)d_in[1];
    float* out = (float*)d_out;

    // ws layout (~9.7 MB)
    ushort* zn    = (ushort*)d_ws;                                  // 2 MB
    float*  dii   = (float*)((char*)d_ws + (size_t)N * D * 2);      // 32 KB
    float*  tpart = dii + N;                                        // 6.55 MB
    float*  cpart = tpart + (size_t)LCH * NLBL * D;                 // 51.2 KB
    float*  t     = cpart + (size_t)LCH * NLBL;                     // 51.2 KB
    float*  cnt   = t + (size_t)NLBL * D;                           // 400 B
    float*  pZ    = cnt + NLBL;                                     // 1 MB

    znorm_kernel<<<N / 4, 256, 0, stream>>>(z, zn, dii);
    labelsum_kernel<<<LCH, 256, 0, stream>>>(zn, y, tpart, cpart);
    reduce_t_kernel<<<NLBL * D / 64 + 1, 256, 0, stream>>>(tpart, cpart, t, cnt);
    supcon_main<<<(NRG * JC) / 4, 256, 0, stream>>>(zn, pZ);
    supcon_finalize<<<N / 4, 256, 0, stream>>>(zn, y, pZ, dii, t, cnt, out);
}

// Round 13
// 51.470 us; speedup vs baseline: 2.0565x; 1.0080x over previous
//
#include <hip/hip_runtime.h>
#include <hip/hip_bf16.h>

#define N 8192
#define D 128
#define JC 32                // j-chunks
#define JCH (N / JC)         // 256 cols per chunk
#define WROWS 128            // rows per wave (8 M-tiles, a[8][4] -> AGPRs)
#define NRG (N / WROWS)      // 64 row-groups
#define NLBL 100             // labels in [0,100)
#define LCH 128              // labelsum blocks
#define LR 64                // rows per labelsum block

#define K1F 14.426950408889634f    // 10 * log2(e)
#define K0F (-14.426950408889634f)

#if __has_builtin(__builtin_amdgcn_exp2f)
#define EXP2(x) __builtin_amdgcn_exp2f(x)
#else
#define EXP2(x) exp2f(x)
#endif

typedef __attribute__((ext_vector_type(8))) short bf16x8;
typedef __attribute__((ext_vector_type(4))) float f32x4;

// ---------------- Stage 0: row-normalize z -> bf16 zn, plus self-dot d_ii ----
__global__ __launch_bounds__(256) void znorm_kernel(const float* __restrict__ z,
                                                    ushort* __restrict__ zn,
                                                    float* __restrict__ dii) {
    const int wid  = threadIdx.x >> 6;
    const int lane = threadIdx.x & 63;
    const int row  = blockIdx.x * 4 + wid;       // grid = N/4 blocks
    const float2 v = reinterpret_cast<const float2*>(z + (size_t)row * D)[lane];
    float ss = v.x * v.x + v.y * v.y;
    #pragma unroll
    for (int m = 1; m < 64; m <<= 1) ss += __shfl_xor(ss, m);
    const float inv = 1.0f / fmaxf(sqrtf(ss), 1e-8f);
    __hip_bfloat16 b0 = __float2bfloat16(v.x * inv);
    __hip_bfloat16 b1 = __float2bfloat16(v.y * inv);
    ushort2 o;
    o.x = *reinterpret_cast<ushort*>(&b0);
    o.y = *reinterpret_cast<ushort*>(&b1);
    reinterpret_cast<ushort2*>(zn + (size_t)row * D)[lane] = o;
    const float f0 = __bfloat162float(b0), f1 = __bfloat162float(b1);
    float s2 = f0 * f0 + f1 * f1;
    #pragma unroll
    for (int m = 1; m < 64; m <<= 1) s2 += __shfl_xor(s2, m);
    if (lane == 0) dii[row] = s2;
}

// ---------------- Stage 0b: per-label sums + histogram (deterministic) ------
__global__ __launch_bounds__(256) void labelsum_kernel(const ushort* __restrict__ zn,
                                                       const int* __restrict__ y,
                                                       float* __restrict__ tpart,
                                                       float* __restrict__ cpart) {
    __shared__ float tl[2][NLBL][D];   // 102.4 KB
    __shared__ float ch[2][128];
    __shared__ int   ly[LR];
    const int h = threadIdx.x >> 7;
    const int d = threadIdx.x & 127;
    for (int c = 0; c < NLBL; ++c) tl[h][c][d] = 0.0f;
    if (threadIdx.x < LR) ly[threadIdx.x] = y[blockIdx.x * LR + threadIdx.x];
    __syncthreads();
    const int j0 = blockIdx.x * LR + h * 32;
    float cl = 0.0f;
    for (int j = 0; j < 32; ++j) {
        const int c = ly[h * 32 + j];
        __hip_bfloat16 hb;
        *reinterpret_cast<ushort*>(&hb) = zn[(size_t)(j0 + j) * D + d];
        tl[h][c][d] += __bfloat162float(hb);      // exclusive column: no race
        cl += (c == d) ? 1.0f : 0.0f;
    }
    ch[h][d] = cl;
    __syncthreads();
    const float* t0 = &tl[0][0][0];
    for (int idx = threadIdx.x; idx < NLBL * D; idx += 256)
        tpart[(size_t)blockIdx.x * NLBL * D + idx] = t0[idx] + t0[NLBL * D + idx];
    if (threadIdx.x < NLBL)
        cpart[blockIdx.x * NLBL + threadIdx.x] = ch[0][threadIdx.x] + ch[1][threadIdx.x];
}

// ---------------- Stage 0c: reduce partials (parallel over outputs) ---------
__global__ __launch_bounds__(256) void reduce_t_kernel(const float* __restrict__ tpart,
                                                       const float* __restrict__ cpart,
                                                       float* __restrict__ t,
                                                       float* __restrict__ cnt) {
    if (blockIdx.x < NLBL * D / 64) {
        __shared__ float s4[4][64];
        const int o  = blockIdx.x * 64 + (threadIdx.x & 63);
        const int sl = threadIdx.x >> 6;           // 4 slices x 32 chunks
        float s = 0.0f;
        #pragma unroll 8
        for (int b = sl * (LCH / 4); b < (sl + 1) * (LCH / 4); ++b)
            s += tpart[(size_t)b * NLBL * D + o];
        s4[sl][threadIdx.x & 63] = s;
        __syncthreads();
        if (threadIdx.x < 64)
            t[blockIdx.x * 64 + threadIdx.x] = s4[0][threadIdx.x] + s4[1][threadIdx.x] +
                                               s4[2][threadIdx.x] + s4[3][threadIdx.x];
    } else {
        const int c = threadIdx.x;
        if (c < NLBL) {
            float s = 0.0f;
            for (int b = 0; b < LCH; ++b) s += cpart[b * NLBL + c];
            cnt[c] = s;
        }
    }
}

// ---------------- Stage 1: streaming MFMA, de-correlated column streams -----
// R12 structure + ONE change: each row-group starts its 16-iteration column
// sweep at iteration (rowGrp & 15), wrapping. Without this, the ~32 in-flight
// waves sharing a chunk march through the SAME cache lines in lockstep ->
// same-line requests serialize at the L2 slice and ALL readers (including
// both waves on a SIMD) stall together -- the measured ~1200-cyc/iter
// correlated stall that R8-R12's scheduling changes couldn't touch.
// Rotation spreads concurrent same-chunk readers across 16 line-sets.
// Per-wave summation order is fixed -> deterministic output.
__global__ __launch_bounds__(256, 2) void supcon_main(const ushort* __restrict__ zn,
                                                      float* __restrict__ pZ) {
    const int wid  = threadIdx.x >> 6;
    const int lane = threadIdx.x & 63;
    const int g    = lane >> 4;      // 0..3
    const int lj   = lane & 15;
    const int gw   = blockIdx.x * 4 + wid;       // 0..2047
    const int rowGrp = gw >> 5;                  // 64 row-groups
    const int chunk  = gw & 31;                  // 32 col-chunks
    const int rowBase = rowGrp * WROWS;
    const int j0 = chunk * JCH;

    // A fragments: 8 M-tiles x 4 K-steps (128 regs -> AGPR file)
    bf16x8 a[8][4];
    #pragma unroll
    for (int m = 0; m < 8; ++m) {
        const ushort* rp = zn + (size_t)(rowBase + m * 16 + lj) * D;
        #pragma unroll
        for (int s = 0; s < 4; ++s)
            a[m][s] = *reinterpret_cast<const bf16x8*>(rp + s * 32 + g * 8);
    }

    float Z[8][4];
    #pragma unroll
    for (int m = 0; m < 8; ++m)
        #pragma unroll
        for (int r = 0; r < 4; ++r) Z[m][r] = 0.0f;

    const f32x4 zero4 = {0.f, 0.f, 0.f, 0.f};
    const ushort* jbase = zn + (size_t)(j0 + lj) * D + g * 8;
    const int it0 = rowGrp & 15;                 // rotated start iteration

    #pragma unroll 1
    for (int k = 0; k < JCH / 16; ++k) {         // 16 iterations, 16 cols each
        const int it = (it0 + k) & 15;
        const ushort* jp = jbase + (size_t)(it * 16) * D;
        bf16x8 b[4];
        #pragma unroll
        for (int s = 0; s < 4; ++s)
            b[s] = *reinterpret_cast<const bf16x8*>(jp + s * 32);
        f32x4 acc[8];
        #pragma unroll
        for (int m = 0; m < 8; ++m) acc[m] = zero4;
        // k-outer / m-inner: adjacent MFMAs independent -> full ILP
        #pragma unroll
        for (int s = 0; s < 4; ++s)
            #pragma unroll
            for (int m = 0; m < 8; ++m)
                acc[m] = __builtin_amdgcn_mfma_f32_16x16x32_bf16(a[m][s], b[s], acc[m], 0, 0, 0);
        #pragma unroll
        for (int m = 0; m < 8; ++m)
            #pragma unroll
            for (int r = 0; r < 4; ++r)
                Z[m][r] += EXP2(fmaf(acc[m][r], K1F, K0F));   // exp(10*dot - 10)
    }

    // sum the 16 cols within each lane group
    #pragma unroll
    for (int m = 0; m < 8; ++m)
        #pragma unroll
        for (int r = 0; r < 4; ++r)
            #pragma unroll
            for (int mk = 1; mk < 16; mk <<= 1)
                Z[m][r] += __shfl_xor(Z[m][r], mk);

    if (lj == 0) {
        #pragma unroll
        for (int m = 0; m < 8; ++m)
            #pragma unroll
            for (int r = 0; r < 4; ++r)
                pZ[chunk * N + rowBase + m * 16 + g * 4 + r] = Z[m][r];
    }
}

// ---------------- Stage 2: finalize loss ----------------
__global__ __launch_bounds__(256) void supcon_finalize(const ushort* __restrict__ zn,
                                                       const int* __restrict__ y,
                                                       const float* __restrict__ pZ,
                                                       const float* __restrict__ dii,
                                                       const float* __restrict__ t,
                                                       const float* __restrict__ cnt,
                                                       float* __restrict__ out) {
    const int wid  = threadIdx.x >> 6;
    const int lane = threadIdx.x & 63;
    const int row  = blockIdx.x * 4 + wid;
    const int c    = y[row];
    const ushort2 u = reinterpret_cast<const ushort2*>(zn + (size_t)row * D)[lane];
    const float2 tv = reinterpret_cast<const float2*>(t + (size_t)c * D)[lane];
    __hip_bfloat16 h0, h1;
    *reinterpret_cast<ushort*>(&h0) = u.x;
    *reinterpret_cast<ushort*>(&h1) = u.y;
    float dot = __bfloat162float(h0) * tv.x + __bfloat162float(h1) * tv.y;
    #pragma unroll
    for (int m = 1; m < 64; m <<= 1) dot += __shfl_xor(dot, m);
    float zs = (lane < JC) ? pZ[lane * N + row] : 0.0f;
    #pragma unroll
    for (int m = 1; m < JC; m <<= 1) zs += __shfl_xor(zs, m);
    if (lane == 0) {
        const float di = dii[row];
        const float zc = zs - EXP2(fmaf(di, K1F, K0F));   // remove self term
        const float cn = cnt[c] - 1.0f;                   // exclude self
        const float S  = dot - di;                        // exclude self
        const float denom = fmaxf(cn, 1.0f);
        const float lse   = 10.0f + logf(zc);
        out[row] = -(10.0f * S) / denom + (cn > 0.5f ? lse : 0.0f);
    }
}

extern "C" void kernel_launch(void* const* d_in, const int* in_sizes, int n_in,
                              void* d_out, int out_size, void* d_ws, size_t ws_size,
                              hipStream_t stream) {
    const float* z = (const float*)d_in[0];
    const int*   y = (const int*)d_in[1];
    float* out = (float*)d_out;

    // ws layout (~9.7 MB)
    ushort* zn    = (ushort*)d_ws;                                  // 2 MB
    float*  dii   = (float*)((char*)d_ws + (size_t)N * D * 2);      // 32 KB
    float*  tpart = dii + N;                                        // 6.55 MB
    float*  cpart = tpart + (size_t)LCH * NLBL * D;                 // 51.2 KB
    float*  t     = cpart + (size_t)LCH * NLBL;                     // 51.2 KB
    float*  cnt   = t + (size_t)NLBL * D;                           // 400 B
    float*  pZ    = cnt + NLBL;                                     // 1 MB

    znorm_kernel<<<N / 4, 256, 0, stream>>>(z, zn, dii);
    labelsum_kernel<<<LCH, 256, 0, stream>>>(zn, y, tpart, cpart);
    reduce_t_kernel<<<NLBL * D / 64 + 1, 256, 0, stream>>>(tpart, cpart, t, cnt);
    supcon_main<<<(NRG * JC) / 4, 256, 0, stream>>>(zn, pZ);
    supcon_finalize<<<N / 4, 256, 0, stream>>>(zn, y, pZ, dii, t, cnt, out);
}

// Round 14
// 46.966 us; speedup vs baseline: 2.2537x; 1.0959x over previous
//
#include <hip/hip_runtime.h>
#include <hip/hip_bf16.h>

#define N 8192
#define D 128
#define JC 16                // j-chunks
#define JCH (N / JC)         // 512 cols per chunk
#define BJ 64                // cols per LDS tile (16 KB)
#define NT (JCH / BJ)        // 8 tiles per chunk
#define RBLK 128             // rows per block (4 waves x 32)
#define NRB (N / RBLK)       // 64 row-blocks
#define NLBL 100             // labels in [0,100)
#define LCH 128              // labelsum blocks
#define LR 64                // rows per labelsum block

#define K1F 14.426950408889634f    // 10 * log2(e)
#define K0F (-14.426950408889634f)

#if __has_builtin(__builtin_amdgcn_exp2f)
#define EXP2(x) __builtin_amdgcn_exp2f(x)
#else
#define EXP2(x) exp2f(x)
#endif

typedef __attribute__((ext_vector_type(8))) short bf16x8;
typedef __attribute__((ext_vector_type(4))) float f32x4;
typedef __attribute__((address_space(1))) const unsigned int gu32;
typedef __attribute__((address_space(3))) unsigned int lu32;

// ---------------- Stage 0: row-normalize z -> bf16 zn, plus self-dot d_ii ----
__global__ __launch_bounds__(256) void znorm_kernel(const float* __restrict__ z,
                                                    ushort* __restrict__ zn,
                                                    float* __restrict__ dii) {
    const int wid  = threadIdx.x >> 6;
    const int lane = threadIdx.x & 63;
    const int row  = blockIdx.x * 4 + wid;       // grid = N/4 blocks
    const float2 v = reinterpret_cast<const float2*>(z + (size_t)row * D)[lane];
    float ss = v.x * v.x + v.y * v.y;
    #pragma unroll
    for (int m = 1; m < 64; m <<= 1) ss += __shfl_xor(ss, m);
    const float inv = 1.0f / fmaxf(sqrtf(ss), 1e-8f);
    __hip_bfloat16 b0 = __float2bfloat16(v.x * inv);
    __hip_bfloat16 b1 = __float2bfloat16(v.y * inv);
    ushort2 o;
    o.x = *reinterpret_cast<ushort*>(&b0);
    o.y = *reinterpret_cast<ushort*>(&b1);
    reinterpret_cast<ushort2*>(zn + (size_t)row * D)[lane] = o;
    const float f0 = __bfloat162float(b0), f1 = __bfloat162float(b1);
    float s2 = f0 * f0 + f1 * f1;
    #pragma unroll
    for (int m = 1; m < 64; m <<= 1) s2 += __shfl_xor(s2, m);
    if (lane == 0) dii[row] = s2;
}

// ---------------- Stage 0b: per-label sums + histogram (deterministic) ------
__global__ __launch_bounds__(256) void labelsum_kernel(const ushort* __restrict__ zn,
                                                       const int* __restrict__ y,
                                                       float* __restrict__ tpart,
                                                       float* __restrict__ cpart) {
    __shared__ float tl[2][NLBL][D];   // 102.4 KB
    __shared__ float ch[2][128];
    __shared__ int   ly[LR];
    const int h = threadIdx.x >> 7;
    const int d = threadIdx.x & 127;
    for (int c = 0; c < NLBL; ++c) tl[h][c][d] = 0.0f;
    if (threadIdx.x < LR) ly[threadIdx.x] = y[blockIdx.x * LR + threadIdx.x];
    __syncthreads();
    const int j0 = blockIdx.x * LR + h * 32;
    float cl = 0.0f;
    for (int j = 0; j < 32; ++j) {
        const int c = ly[h * 32 + j];
        __hip_bfloat16 hb;
        *reinterpret_cast<ushort*>(&hb) = zn[(size_t)(j0 + j) * D + d];
        tl[h][c][d] += __bfloat162float(hb);      // exclusive column: no race
        cl += (c == d) ? 1.0f : 0.0f;
    }
    ch[h][d] = cl;
    __syncthreads();
    const float* t0 = &tl[0][0][0];
    for (int idx = threadIdx.x; idx < NLBL * D; idx += 256)
        tpart[(size_t)blockIdx.x * NLBL * D + idx] = t0[idx] + t0[NLBL * D + idx];
    if (threadIdx.x < NLBL)
        cpart[blockIdx.x * NLBL + threadIdx.x] = ch[0][threadIdx.x] + ch[1][threadIdx.x];
}

// ---------------- Stage 0c: reduce partials (parallel over outputs) ---------
__global__ __launch_bounds__(256) void reduce_t_kernel(const float* __restrict__ tpart,
                                                       const float* __restrict__ cpart,
                                                       float* __restrict__ t,
                                                       float* __restrict__ cnt) {
    if (blockIdx.x < NLBL * D / 64) {
        __shared__ float s4[4][64];
        const int o  = blockIdx.x * 64 + (threadIdx.x & 63);
        const int sl = threadIdx.x >> 6;           // 4 slices x 32 chunks
        float s = 0.0f;
        #pragma unroll 8
        for (int b = sl * (LCH / 4); b < (sl + 1) * (LCH / 4); ++b)
            s += tpart[(size_t)b * NLBL * D + o];
        s4[sl][threadIdx.x & 63] = s;
        __syncthreads();
        if (threadIdx.x < 64)
            t[blockIdx.x * 64 + threadIdx.x] = s4[0][threadIdx.x] + s4[1][threadIdx.x] +
                                               s4[2][threadIdx.x] + s4[3][threadIdx.x];
    } else {
        const int c = threadIdx.x;
        if (c < NLBL) {
            float s = 0.0f;
            for (int b = 0; b < LCH; ++b) s += cpart[b * NLBL + c];
            cnt[c] = s;
        }
    }
}

// ---------------- Stage 1: glds-staged LDS B, double-buffered ----------------
// m97-analog. 4 waves x 32 rows; B tile (64 cols x 128 dims, 16 KB) staged by
// global_load_lds width=16 (async DMA, no VGPR round-trip, no staging regs ->
// no spill, unlike R6/R11). Double-buffered; ONE vmcnt(0)+barrier per tile,
// amortized over ~1100 cyc of compute. Rule #21 swizzle: LDS dest linear
// (HW requirement), global SOURCE pre-swizzled slot^=(row&7), ds_read applies
// the same XOR -> identity mapping, uniform 8 lanes/bank-group (b128 floor).
// ~100 regs/wave, 4 blocks/CU (LDS 32 KB), 4 waves/SIMD.
__global__ __launch_bounds__(256, 4) void supcon_main(const ushort* __restrict__ zn,
                                                      float* __restrict__ pZ) {
    __shared__ ushort Bsm[2][BJ * D];   // 2 x 16 KB
    const int wid  = threadIdx.x >> 6;
    const int lane = threadIdx.x & 63;
    const int g    = lane >> 4;      // 0..3
    const int lj   = lane & 15;
    const int rowBlk = blockIdx.x & (NRB - 1);   // 64 row-blocks
    const int chunk  = blockIdx.x >> 6;          // 16 chunks
    const int rowBase = rowBlk * RBLK + wid * 32;
    const int j0 = chunk * JCH;

    // A fragments: 2 M-tiles x 4 K-steps (32 VGPR)
    bf16x8 a[2][4];
    #pragma unroll
    for (int m = 0; m < 2; ++m) {
        const ushort* rp = zn + (size_t)(rowBase + m * 16 + lj) * D;
        #pragma unroll
        for (int s = 0; s < 4; ++s)
            a[m][s] = *reinterpret_cast<const bf16x8*>(rp + s * 32 + g * 8);
    }

    float Z[2][4];
    #pragma unroll
    for (int m = 0; m < 2; ++m)
        #pragma unroll
        for (int r = 0; r < 4; ++r) Z[m][r] = 0.0f;

    // stage tile jt into Bsm[buf]: per wave 4 glds calls (1 KB each).
    // call c: LDS linear bytes [(wid*4+c)*1024 + lane*16); row=(wid*16+c*4+lane/16)
    const int lrow4 = lane >> 4;                 // 0..3
    const int sslot = lane & 15;
    auto STAGE = [&](int buf, int jt) {
        #pragma unroll
        for (int c = 0; c < 4; ++c) {
            const int row = wid * 16 + c * 4 + lrow4;
            const ushort* src = zn + (size_t)(j0 + jt * BJ + row) * D
                                + ((sslot ^ (row & 7)) * 8);
            __builtin_amdgcn_global_load_lds(
                (gu32*)src, (lu32*)&Bsm[buf][(wid * 4 + c) * 512], 16, 0, 0);
        }
    };

    const f32x4 zero4 = {0.f, 0.f, 0.f, 0.f};
    auto COMPUTE = [&](int buf) {
        #pragma unroll
        for (int jt = 0; jt < 4; ++jt) {
            const int row = jt * 16 + lj;
            const int rx  = row & 7;
            bf16x8 b[4];
            #pragma unroll
            for (int s = 0; s < 4; ++s)
                b[s] = *reinterpret_cast<const bf16x8*>(
                    &Bsm[buf][row * D + (((s * 4 + g) ^ rx) * 8)]);
            f32x4 acc[2] = {zero4, zero4};
            #pragma unroll
            for (int s = 0; s < 4; ++s)
                #pragma unroll
                for (int m = 0; m < 2; ++m)
                    acc[m] = __builtin_amdgcn_mfma_f32_16x16x32_bf16(a[m][s], b[s], acc[m], 0, 0, 0);
            #pragma unroll
            for (int m = 0; m < 2; ++m)
                #pragma unroll
                for (int r = 0; r < 4; ++r)
                    Z[m][r] += EXP2(fmaf(acc[m][r], K1F, K0F));   // exp(10*dot-10)
        }
    };

    // prologue
    STAGE(0, 0);
    asm volatile("s_waitcnt vmcnt(0)");
    __syncthreads();
    int cur = 0;
    #pragma unroll 1
    for (int t = 0; t < NT; ++t) {
        if (t + 1 < NT) STAGE(cur ^ 1, t + 1);   // async DMA under compute
        COMPUTE(cur);
        if (t + 1 < NT) { asm volatile("s_waitcnt vmcnt(0)"); }
        __syncthreads();
        cur ^= 1;
    }

    // sum the 16 cols within each lane group
    #pragma unroll
    for (int m = 0; m < 2; ++m)
        #pragma unroll
        for (int r = 0; r < 4; ++r)
            #pragma unroll
            for (int mk = 1; mk < 16; mk <<= 1)
                Z[m][r] += __shfl_xor(Z[m][r], mk);

    if (lj == 0) {
        #pragma unroll
        for (int m = 0; m < 2; ++m)
            #pragma unroll
            for (int r = 0; r < 4; ++r)
                pZ[chunk * N + rowBase + m * 16 + g * 4 + r] = Z[m][r];
    }
}

// ---------------- Stage 2: finalize loss ----------------
__global__ __launch_bounds__(256) void supcon_finalize(const ushort* __restrict__ zn,
                                                       const int* __restrict__ y,
                                                       const float* __restrict__ pZ,
                                                       const float* __restrict__ dii,
                                                       const float* __restrict__ t,
                                                       const float* __restrict__ cnt,
                                                       float* __restrict__ out) {
    const int wid  = threadIdx.x >> 6;
    const int lane = threadIdx.x & 63;
    const int row  = blockIdx.x * 4 + wid;
    const int c    = y[row];
    const ushort2 u = reinterpret_cast<const ushort2*>(zn + (size_t)row * D)[lane];
    const float2 tv = reinterpret_cast<const float2*>(t + (size_t)c * D)[lane];
    __hip_bfloat16 h0, h1;
    *reinterpret_cast<ushort*>(&h0) = u.x;
    *reinterpret_cast<ushort*>(&h1) = u.y;
    float dot = __bfloat162float(h0) * tv.x + __bfloat162float(h1) * tv.y;
    #pragma unroll
    for (int m = 1; m < 64; m <<= 1) dot += __shfl_xor(dot, m);
    float zs = (lane < JC) ? pZ[lane * N + row] : 0.0f;
    #pragma unroll
    for (int m = 1; m < JC; m <<= 1) zs += __shfl_xor(zs, m);
    if (lane == 0) {
        const float di = dii[row];
        const float zc = zs - EXP2(fmaf(di, K1F, K0F));   // remove self term
        const float cn = cnt[c] - 1.0f;                   // exclude self
        const float S  = dot - di;                        // exclude self
        const float denom = fmaxf(cn, 1.0f);
        const float lse   = 10.0f + logf(zc);
        out[row] = -(10.0f * S) / denom + (cn > 0.5f ? lse : 0.0f);
    }
}

extern "C" void kernel_launch(void* const* d_in, const int* in_sizes, int n_in,
                              void* d_out, int out_size, void* d_ws, size_t ws_size,
                              hipStream_t stream) {
    const float* z = (const float*)d_in[0];
    const int*   y = (const int*)d_in[1];
    float* out = (float*)d_out;

    // ws layout (~9.2 MB)
    ushort* zn    = (ushort*)d_ws;                                  // 2 MB
    float*  dii   = (float*)((char*)d_ws + (size_t)N * D * 2);      // 32 KB
    float*  tpart = dii + N;                                        // 6.55 MB
    float*  cpart = tpart + (size_t)LCH * NLBL * D;                 // 51.2 KB
    float*  t     = cpart + (size_t)LCH * NLBL;                     // 51.2 KB
    float*  cnt   = t + (size_t)NLBL * D;                           // 400 B
    float*  pZ    = cnt + NLBL;                                     // 512 KB

    znorm_kernel<<<N / 4, 256, 0, stream>>>(z, zn, dii);
    labelsum_kernel<<<LCH, 256, 0, stream>>>(zn, y, tpart, cpart);
    reduce_t_kernel<<<NLBL * D / 64 + 1, 256, 0, stream>>>(tpart, cpart, t, cnt);
    supcon_main<<<NRB * JC, 256, 0, stream>>>(zn, pZ);
    supcon_finalize<<<N / 4, 256, 0, stream>>>(zn, y, pZ, dii, t, cnt, out);
}

// Round 15
// 43.187 us; speedup vs baseline: 2.4509x; 1.0875x over previous
//
#include <hip/hip_runtime.h>
#include <hip/hip_bf16.h>

#define N 8192
#define D 128
#define NG 64                // 128-row groups
#define NTILE 2080           // NG*(NG+1)/2 upper-triangle tiles
#define NLBL 100             // labels in [0,100)
#define LCH 128              // labelsum blocks
#define LR 64                // rows per labelsum block

#define K1F 14.426950408889634f    // 10 * log2(e)
#define K0F (-14.426950408889634f)

#if __has_builtin(__builtin_amdgcn_exp2f)
#define EXP2(x) __builtin_amdgcn_exp2f(x)
#else
#define EXP2(x) exp2f(x)
#endif

typedef __attribute__((ext_vector_type(8))) short bf16x8;
typedef __attribute__((ext_vector_type(4))) float f32x4;
typedef __attribute__((address_space(1))) const unsigned int gu32;
typedef __attribute__((address_space(3))) unsigned int lu32;

// ---------------- Stage 0: row-normalize z -> bf16 zn, plus self-dot d_ii ----
__global__ __launch_bounds__(256) void znorm_kernel(const float* __restrict__ z,
                                                    ushort* __restrict__ zn,
                                                    float* __restrict__ dii) {
    const int wid  = threadIdx.x >> 6;
    const int lane = threadIdx.x & 63;
    const int row  = blockIdx.x * 4 + wid;       // grid = N/4 blocks
    const float2 v = reinterpret_cast<const float2*>(z + (size_t)row * D)[lane];
    float ss = v.x * v.x + v.y * v.y;
    #pragma unroll
    for (int m = 1; m < 64; m <<= 1) ss += __shfl_xor(ss, m);
    const float inv = 1.0f / fmaxf(sqrtf(ss), 1e-8f);
    __hip_bfloat16 b0 = __float2bfloat16(v.x * inv);
    __hip_bfloat16 b1 = __float2bfloat16(v.y * inv);
    ushort2 o;
    o.x = *reinterpret_cast<ushort*>(&b0);
    o.y = *reinterpret_cast<ushort*>(&b1);
    reinterpret_cast<ushort2*>(zn + (size_t)row * D)[lane] = o;
    const float f0 = __bfloat162float(b0), f1 = __bfloat162float(b1);
    float s2 = f0 * f0 + f1 * f1;
    #pragma unroll
    for (int m = 1; m < 64; m <<= 1) s2 += __shfl_xor(s2, m);
    if (lane == 0) dii[row] = s2;
}

// ---------------- Stage 0b: per-label sums + histogram (deterministic) ------
__global__ __launch_bounds__(256) void labelsum_kernel(const ushort* __restrict__ zn,
                                                       const int* __restrict__ y,
                                                       float* __restrict__ tpart,
                                                       float* __restrict__ cpart) {
    __shared__ float tl[2][NLBL][D];   // 102.4 KB
    __shared__ float ch[2][128];
    __shared__ int   ly[LR];
    const int h = threadIdx.x >> 7;
    const int d = threadIdx.x & 127;
    for (int c = 0; c < NLBL; ++c) tl[h][c][d] = 0.0f;
    if (threadIdx.x < LR) ly[threadIdx.x] = y[blockIdx.x * LR + threadIdx.x];
    __syncthreads();
    const int j0 = blockIdx.x * LR + h * 32;
    float cl = 0.0f;
    for (int j = 0; j < 32; ++j) {
        const int c = ly[h * 32 + j];
        __hip_bfloat16 hb;
        *reinterpret_cast<ushort*>(&hb) = zn[(size_t)(j0 + j) * D + d];
        tl[h][c][d] += __bfloat162float(hb);      // exclusive column: no race
        cl += (c == d) ? 1.0f : 0.0f;
    }
    ch[h][d] = cl;
    __syncthreads();
    const float* t0 = &tl[0][0][0];
    for (int idx = threadIdx.x; idx < NLBL * D; idx += 256)
        tpart[(size_t)blockIdx.x * NLBL * D + idx] = t0[idx] + t0[NLBL * D + idx];
    if (threadIdx.x < NLBL)
        cpart[blockIdx.x * NLBL + threadIdx.x] = ch[0][threadIdx.x] + ch[1][threadIdx.x];
}

// ---------------- Stage 0c: reduce partials (parallel over outputs) ---------
__global__ __launch_bounds__(256) void reduce_t_kernel(const float* __restrict__ tpart,
                                                       const float* __restrict__ cpart,
                                                       float* __restrict__ t,
                                                       float* __restrict__ cnt) {
    if (blockIdx.x < NLBL * D / 64) {
        __shared__ float s4[4][64];
        const int o  = blockIdx.x * 64 + (threadIdx.x & 63);
        const int sl = threadIdx.x >> 6;           // 4 slices x 32 chunks
        float s = 0.0f;
        #pragma unroll 8
        for (int b = sl * (LCH / 4); b < (sl + 1) * (LCH / 4); ++b)
            s += tpart[(size_t)b * NLBL * D + o];
        s4[sl][threadIdx.x & 63] = s;
        __syncthreads();
        if (threadIdx.x < 64)
            t[blockIdx.x * 64 + threadIdx.x] = s4[0][threadIdx.x] + s4[1][threadIdx.x] +
                                               s4[2][threadIdx.x] + s4[3][threadIdx.x];
    } else {
        const int c = threadIdx.x;
        if (c < NLBL) {
            float s = 0.0f;
            for (int b = 0; b < LCH; ++b) s += cpart[b * NLBL + c];
            cnt[c] = s;
        }
    }
}

// ---------------- Stage 1: UPPER-TRIANGLE tiled exp-sum (symmetry: 2x less) --
// sim is symmetric -> process only tiles (r,c), r<=c, of the 64x64 tile grid
// (2080 of 4096). Each 128x128 tile contributes its exp values to BOTH
// Z-rows (group r) and, via in-tile column reduction, Z-cols (group c).
// Partials P[64][N]: tile(r,c) writes row-partials P[c][rows of r] and (r<c)
// col-partials P[r][cols of c]. Every P[k][i] has EXACTLY ONE writer
// (tile (min,max) of (i>>7,k)) -> deterministic, no atomics, no zero-init.
// B staged via global_load_lds (R14's verified swizzle: linear LDS dest,
// pre-swizzled source slot^=(row&7), same XOR on ds_read).
__global__ __launch_bounds__(256, 4) void supcon_main(const ushort* __restrict__ zn,
                                                      float* __restrict__ P) {
    __shared__ ushort Bsm[128 * D];     // 32 KB
    __shared__ float  zcLDS[4][128];    // 2 KB
    const int wid  = threadIdx.x >> 6;
    const int lane = threadIdx.x & 63;
    const int g    = lane >> 4;      // 0..3
    const int lj   = lane & 15;

    // decode tile index -> (r, c): t = r*(129-r)/2 + (c-r)
    const int t = blockIdx.x;
    int r = (int)((129.0f - sqrtf(16641.0f - 8.0f * (float)t)) * 0.5f);
    r = r < 0 ? 0 : (r > 63 ? 63 : r);
    while (r > 0 && (r * (129 - r)) / 2 > t) --r;
    while (((r + 1) * (129 - (r + 2))) / 2 + (r + 1) <= t) ++r;  // base(r+1)<=t
    const int c = r + (t - (r * (129 - r)) / 2);

    const int rowBase = r * 128 + wid * 32;      // this wave's 32 A-rows
    const size_t colBase = (size_t)c * 128;

    // stage B tile (128 cols x 128 dims = 32 KB): per wave rows wid*32..+32,
    // 8 glds calls of 1 KB; LDS dest linear, source pre-swizzled
    const int lrow4 = lane >> 4;
    const int sslot = lane & 15;
    #pragma unroll
    for (int c2 = 0; c2 < 8; ++c2) {
        const int row = wid * 32 + c2 * 4 + lrow4;
        const ushort* src = zn + (colBase + row) * D + ((sslot ^ (row & 7)) * 8);
        __builtin_amdgcn_global_load_lds((gu32*)src,
                                         (lu32*)&Bsm[(wid * 8 + c2) * 512], 16, 0, 0);
    }

    // A fragments: 2 M-tiles x 4 K-steps (32 VGPR)
    bf16x8 a[2][4];
    #pragma unroll
    for (int m = 0; m < 2; ++m) {
        const ushort* rp = zn + (size_t)(rowBase + m * 16 + lj) * D;
        #pragma unroll
        for (int s = 0; s < 4; ++s)
            a[m][s] = *reinterpret_cast<const bf16x8*>(rp + s * 32 + g * 8);
    }

    float Zrow[2][4];
    #pragma unroll
    for (int m = 0; m < 2; ++m)
        #pragma unroll
        for (int rr = 0; rr < 4; ++rr) Zrow[m][rr] = 0.0f;
    float zcol[8];

    asm volatile("s_waitcnt vmcnt(0)");
    __syncthreads();

    const f32x4 zero4 = {0.f, 0.f, 0.f, 0.f};
    #pragma unroll
    for (int jt = 0; jt < 8; ++jt) {             // 8 x 16-col sub-tiles
        const int brow = jt * 16 + lj;           // B column index in tile
        const int rx   = brow & 7;
        bf16x8 b[4];
        #pragma unroll
        for (int s = 0; s < 4; ++s)
            b[s] = *reinterpret_cast<const bf16x8*>(
                &Bsm[brow * D + (((s * 4 + g) ^ rx) * 8)]);
        f32x4 acc[2] = {zero4, zero4};
        #pragma unroll
        for (int s = 0; s < 4; ++s)
            #pragma unroll
            for (int m = 0; m < 2; ++m)
                acc[m] = __builtin_amdgcn_mfma_f32_16x16x32_bf16(a[m][s], b[s], acc[m], 0, 0, 0);
        float esum = 0.0f;
        #pragma unroll
        for (int m = 0; m < 2; ++m)
            #pragma unroll
            for (int rr = 0; rr < 4; ++rr) {
                const float e = EXP2(fmaf(acc[m][rr], K1F, K0F));  // exp(10*dot-10)
                Zrow[m][rr] += e;
                esum += e;
            }
        zcol[jt] = esum;   // col jt*16+lj, summed over this lane's 8 rows
    }

    // row side: reduce over the 16 cols (lj) of each group; write P[c][rows r]
    #pragma unroll
    for (int m = 0; m < 2; ++m)
        #pragma unroll
        for (int rr = 0; rr < 4; ++rr)
            #pragma unroll
            for (int mk = 1; mk < 16; mk <<= 1)
                Zrow[m][rr] += __shfl_xor(Zrow[m][rr], mk);
    if (lj == 0) {
        #pragma unroll
        for (int m = 0; m < 2; ++m)
            #pragma unroll
            for (int rr = 0; rr < 4; ++rr)
                P[(size_t)c * N + rowBase + m * 16 + g * 4 + rr] = Zrow[m][rr];
    }

    // col side (off-diagonal only): reduce over g (rows) -> P[r][cols of c]
    if (r != c) {
        #pragma unroll
        for (int jt = 0; jt < 8; ++jt) {
            zcol[jt] += __shfl_xor(zcol[jt], 16);
            zcol[jt] += __shfl_xor(zcol[jt], 32);
        }
        if (lane < 16) {
            #pragma unroll
            for (int jt = 0; jt < 8; ++jt)
                zcLDS[wid][jt * 16 + lane] = zcol[jt];
        }
        __syncthreads();
        if (threadIdx.x < 128) {
            const float s = zcLDS[0][threadIdx.x] + zcLDS[1][threadIdx.x] +
                            zcLDS[2][threadIdx.x] + zcLDS[3][threadIdx.x];
            P[(size_t)r * N + colBase + threadIdx.x] = s;
        }
    }
}

// ---------------- Stage 2: finalize loss ----------------
__global__ __launch_bounds__(256) void supcon_finalize(const ushort* __restrict__ zn,
                                                       const int* __restrict__ y,
                                                       const float* __restrict__ P,
                                                       const float* __restrict__ dii,
                                                       const float* __restrict__ t,
                                                       const float* __restrict__ cnt,
                                                       float* __restrict__ out) {
    const int wid  = threadIdx.x >> 6;
    const int lane = threadIdx.x & 63;
    const int row  = blockIdx.x * 4 + wid;
    const int c    = y[row];
    const ushort2 u = reinterpret_cast<const ushort2*>(zn + (size_t)row * D)[lane];
    const float2 tv = reinterpret_cast<const float2*>(t + (size_t)c * D)[lane];
    __hip_bfloat16 h0, h1;
    *reinterpret_cast<ushort*>(&h0) = u.x;
    *reinterpret_cast<ushort*>(&h1) = u.y;
    float dot = __bfloat162float(h0) * tv.x + __bfloat162float(h1) * tv.y;
    #pragma unroll
    for (int m = 1; m < 64; m <<= 1) dot += __shfl_xor(dot, m);
    // 64 partials, one per lane
    float zs = P[(size_t)lane * N + row];
    #pragma unroll
    for (int m = 1; m < 64; m <<= 1) zs += __shfl_xor(zs, m);
    if (lane == 0) {
        const float di = dii[row];
        const float zc = zs - EXP2(fmaf(di, K1F, K0F));   // remove self term
        const float cn = cnt[c] - 1.0f;                   // exclude self
        const float S  = dot - di;                        // exclude self
        const float denom = fmaxf(cn, 1.0f);
        const float lse   = 10.0f + logf(zc);
        out[row] = -(10.0f * S) / denom + (cn > 0.5f ? lse : 0.0f);
    }
}

extern "C" void kernel_launch(void* const* d_in, const int* in_sizes, int n_in,
                              void* d_out, int out_size, void* d_ws, size_t ws_size,
                              hipStream_t stream) {
    const float* z = (const float*)d_in[0];
    const int*   y = (const int*)d_in[1];
    float* out = (float*)d_out;

    // ws layout (~10.7 MB)
    ushort* zn    = (ushort*)d_ws;                                  // 2 MB
    float*  dii   = (float*)((char*)d_ws + (size_t)N * D * 2);      // 32 KB
    float*  tpart = dii + N;                                        // 6.55 MB
    float*  cpart = tpart + (size_t)LCH * NLBL * D;                 // 51.2 KB
    float*  t     = cpart + (size_t)LCH * NLBL;                     // 51.2 KB
    float*  cnt   = t + (size_t)NLBL * D;                           // 400 B
    float*  P     = cnt + NLBL;                                     // 2 MB (64 x N)

    znorm_kernel<<<N / 4, 256, 0, stream>>>(z, zn, dii);
    labelsum_kernel<<<LCH, 256, 0, stream>>>(zn, y, tpart, cpart);
    reduce_t_kernel<<<NLBL * D / 64 + 1, 256, 0, stream>>>(tpart, cpart, t, cnt);
    supcon_main<<<NTILE, 256, 0, stream>>>(zn, P);
    supcon_finalize<<<N / 4, 256, 0, stream>>>(zn, y, P, dii, t, cnt, out);
}